// Round 1
// 655.594 us; speedup vs baseline: 1.0308x; 1.0308x over previous
//
#include <hip/hip_runtime.h>

typedef unsigned short u16;
typedef unsigned int u32;
typedef short short8 __attribute__((ext_vector_type(8)));
typedef float f32x4 __attribute__((ext_vector_type(4)));

#define HW 128

__device__ __forceinline__ float bf2f(u16 h) {
    u32 u = ((u32)h) << 16;
    return __uint_as_float(u);
}
__device__ __forceinline__ u16 f2bf(float f) {
    u32 u = __float_as_uint(f);
    u32 r = (u + 0x7FFFu + ((u >> 16) & 1u)) >> 16;
    return (u16)r;
}
__device__ __forceinline__ float lrelu_f(float v) {
    return v >= 0.f ? v : 0.1f * v;
}

// async global -> LDS, 16B per lane. LDS dest must be WAVE-UNIFORM base; HW adds lane*16.
__device__ __forceinline__ void gload_lds16(const void* g, void* l) {
    __builtin_amdgcn_global_load_lds((const __attribute__((address_space(1))) void*)g,
                                     (__attribute__((address_space(3))) void*)l, 16, 0, 0);
}

// ---------------- weight pack for MFMA convs: [oc][ic][3][3] f32 -> [tap][ch][quad][oc][j8] bf16
template<int ICR, int ICP, int OC>
__global__ __launch_bounds__(256) void pack_w(const float* __restrict__ w, u16* __restrict__ dst) {
    constexpr int NCH = ICP / 32;
    constexpr int NTOT = 9 * NCH * 4 * OC * 8;
    int gid = blockIdx.x * 256 + threadIdx.x;
    if (gid >= NTOT) return;
    int j = gid & 7;
    int t = gid >> 3;
    int oc = t % OC; t /= OC;
    int quad = t & 3; t >>= 2;
    int ch = t % NCH;
    int tap = t / NCH;
    int ic = ch * 32 + quad * 8 + j;
    int ky = tap / 3, kx = tap % 3;
    float v = (ic < ICR) ? w[((oc * ICR + ic) * 3 + ky) * 3 + kx] : 0.f;
    dst[gid] = f2bf(v);
}

// ---------------- conv4 weight pack: [2][32][5][5] f32 -> [tap(25)][oc(2)][ic(32)] f32
__global__ __launch_bounds__(256) void pack_w4(const float* __restrict__ w, float* __restrict__ dst) {
    int gid = blockIdx.x * 256 + threadIdx.x;
    if (gid >= 1600) return;
    int ic = gid & 31;
    int t = gid >> 5;
    int oc = t & 1;
    int tap = t >> 1;
    dst[(tap * 2 + oc) * 32 + ic] = w[(oc * 32 + ic) * 25 + tap];
}

// ---------------- upflow: transposed conv, lhs_dilation=2, pad=2, k=4, groups=2
__global__ __launch_bounds__(256) void upflow_kernel(const float* __restrict__ tflow, const float* __restrict__ wu,
                                                     float* __restrict__ flow) {
    int gid = blockIdx.x * 256 + threadIdx.x;   // 524288 exact
    int x = gid & 127;
    int y = (gid >> 7) & 127;
    int c = (gid >> 14) & 1;
    int b = gid >> 15;
    float acc = 0.f;
#pragma unroll
    for (int ky = 0; ky < 4; ++ky) {
        int u = y + ky - 2;
        if ((u & 1) || u < 0 || u > 126) continue;
        int iy = u >> 1;
#pragma unroll
        for (int kx = 0; kx < 4; ++kx) {
            int v = x + kx - 2;
            if ((v & 1) || v < 0 || v > 126) continue;
            int ix = v >> 1;
            acc += tflow[((b * 2 + c) * 64 + iy) * 64 + ix] *
                   wu[c * 16 + (3 - ky) * 4 + (3 - kx)];
        }
    }
    flow[gid] = acc;
}

// ---------------- backward warp -> fragment-native bf16 feat2 [b][row 134][cg 12][x 144][8]
__global__ __launch_bounds__(256) void warp_kernel(const float* __restrict__ second, const float* __restrict__ flow,
                                                   u16* __restrict__ feat2) {
    int tid = threadIdx.x;
    int x = tid & 127;
    int half = tid >> 7;            // 0..1
    int blk = blockIdx.x;           // (b*128 + y)*6 + cgp
    int cgp = blk % 6;
    int t = blk / 6;
    int y = t & 127;
    int b = t >> 7;
    int cg = cgp * 2 + half;        // 0..11

    float fx = (float)x + 2.5f * flow[((b * 2 + 0) * HW + y) * HW + x];
    float fy = (float)y + 2.5f * flow[((b * 2 + 1) * HW + y) * HW + x];
    float x0f = floorf(fx), y0f = floorf(fy);
    int x0 = (int)x0f, y0 = (int)y0f;
    int x1 = x0 + 1, y1 = y0 + 1;
    float wx1 = fx - x0f, wx0 = (x0f + 1.f) - fx;
    float wy1 = fy - y0f, wy0 = (y0f + 1.f) - fy;
    float wA = wx0 * wy0, wB = wx1 * wy0, wC = wx0 * wy1, wD = wx1 * wy1;
    float vA = (x0 >= 0 && x0 <= 127 && y0 >= 0 && y0 <= 127) ? 1.f : 0.f;
    float vB = (x1 >= 0 && x1 <= 127 && y0 >= 0 && y0 <= 127) ? 1.f : 0.f;
    float vC = (x0 >= 0 && x0 <= 127 && y1 >= 0 && y1 <= 127) ? 1.f : 0.f;
    float vD = (x1 >= 0 && x1 <= 127 && y1 >= 0 && y1 <= 127) ? 1.f : 0.f;
    wA *= vA; wB *= vB; wC *= vC; wD *= vD;
    float ones = wA + wB + wC + wD;
    float maskf = (ones > 0.999f) ? 1.f : 0.f;
    wA *= maskf; wB *= maskf; wC *= maskf; wD *= maskf;
    int xc0 = min(max(x0, 0), 127), xc1 = min(max(x1, 0), 127);
    int yc0 = min(max(y0, 0), 127), yc1 = min(max(y1, 0), 127);
    int i00 = yc0 * HW + xc0, i01 = yc0 * HW + xc1;
    int i10 = yc1 * HW + xc0, i11 = yc1 * HW + xc1;

    const float* base = second + (size_t)b * 96 * HW * HW + (size_t)(cg * 8) * (HW * HW);
    short8 o;
#pragma unroll
    for (int j = 0; j < 8; ++j) {
        const float* pp = base + (size_t)j * (HW * HW);
        float v = wA * pp[i00] + wB * pp[i01] + wC * pp[i10] + wD * pp[i11];
        o[j] = (short)f2bf(v);
    }
    *(short8*)(feat2 + ((((size_t)(b * 134) + y + 3) * 12 + cg) * 144 + (x + 3)) * 8) = o;
}

// ---------------- correlation as banded MFMA GEMM -> NHWC (16,130,130,64) bf16 corr, + /96 + lrelu
__global__ __launch_bounds__(256) void corr_mfma(const float* __restrict__ first, const u16* __restrict__ feat2,
                                                 u16* __restrict__ corrp) {
    int tid = threadIdx.x;
    int wave = tid >> 6, lane = tid & 63;
    int quad = lane >> 4, l16 = lane & 15;
    int blk = blockIdx.x;            // 16 * 128 * 2 = 4096
    int half = blk & 1;
    int y = (blk >> 1) & 127;
    int b = blk >> 8;
    int x0 = (half * 4 + wave) * 16;

    short8 afr[3];
    const float* fbase = first + ((size_t)(b * 96) * HW + y) * HW + x0 + l16;
#pragma unroll
    for (int ch = 0; ch < 3; ++ch) {
        short8 a;
#pragma unroll
        for (int j = 0; j < 8; ++j)
            a[j] = (short)f2bf(fbase[(size_t)(ch * 32 + quad * 8 + j) * (HW * HW)]);
        afr[ch] = a;
    }

    f32x4 acc[7][2];
#pragma unroll
    for (int dy = 0; dy < 7; ++dy) {
        acc[dy][0] = (f32x4){0.f, 0.f, 0.f, 0.f};
        acc[dy][1] = (f32x4){0.f, 0.f, 0.f, 0.f};
    }

#pragma unroll
    for (int dy = 0; dy < 7; ++dy) {
#pragma unroll
        for (int ch = 0; ch < 3; ++ch) {
            const u16* rp = feat2 + ((((size_t)(b * 134) + y + dy) * 12 + ch * 4 + quad) * 144 + x0 + l16) * 8;
            short8 b0 = *(const short8*)(rp);
            short8 b1 = *(const short8*)(rp + 16 * 8);
            acc[dy][0] = __builtin_amdgcn_mfma_f32_16x16x32_bf16(afr[ch], b0, acc[dy][0], 0, 0, 0);
            acc[dy][1] = __builtin_amdgcn_mfma_f32_16x16x32_bf16(afr[ch], b1, acc[dy][1], 0, 0, 0);
        }
    }

    u16* op = corrp + ((size_t)(b * 130) + y + 1) * (130 * 64);
#pragma unroll
    for (int dy = 0; dy < 7; ++dy)
#pragma unroll
        for (int nt = 0; nt < 2; ++nt)
#pragma unroll
            for (int r = 0; r < 4; ++r) {
                int m = quad * 4 + r;
                int dx = nt * 16 + l16 - m;
                if (dx >= 0 && dx < 7) {
                    float v = lrelu_f(acc[dy][nt][r] * (1.f / 96.f));
                    op[(size_t)(x0 + m + 1) * 64 + dy * 7 + dx] = f2bf(v);
                }
            }
}

// ---------------- MFMA conv 3x3: 2-phase double-buffered LDS (m97 structure)
// Per block: 2 output rows x 128 px x OCB oc. K-steps = 9 taps x (ICP/32) ch-groups.
// Each step stages A (2 rows x 128 px x 32 ch, 16KB) + B (4KB/2KB) into back buffer
// via global_load_lds w=16, computes front buffer from LDS: 8 ds_read_b128 + 16 MFMA.
template<int ICP, int OC, int OCB, int PADOUT>
__global__ __launch_bounds__(256) void conv_mfma(const u16* __restrict__ in, const u16* __restrict__ wp,
                                                 const float* __restrict__ bias, u16* __restrict__ out) {
    constexpr int NCH = ICP / 32;
    constexpr int NOCT = OCB / 16;
    constexpr int OCG = OC / OCB;
    constexpr int Wi = 130;
    constexpr int Wo = 128 + 2 * PADOUT;
    constexpr int NS = 9 * NCH;

    // double-buffered tiles; A layout [buf][row][px][ch32] (64B px-stride, m97 layout)
    __shared__ __align__(16) u16 ldsA[2][2][128][32];
    __shared__ __align__(16) u16 ldsB[2][4 * OCB * 8];

    int tid = threadIdx.x;
    int wave = tid >> 6, lane = tid & 63;
    int quad = lane >> 4, l16 = lane & 15;
    int rowpair = blockIdx.x & 63;
    int t = blockIdx.x >> 6;
    int ocg = t % OCG;
    int b = t / OCG;
    int row_blk = rowpair * 2;
    int row_h = wave >> 1;          // wave's output row within the pair
    int px0 = (wave & 1) * 64;      // wave's 64-px half

    // per-lane staging decomposition: lane -> (px within 16-chunk, channel quarter)
    int pxl = lane >> 2;            // 0..15
    int qq  = lane & 3;             // 0..3 (8 channels each)

    auto stageA = [&](int s, int pb) {
        int ch = s & (NCH - 1);
        int tap = s / NCH;
        int ky = tap / 3, kx = tap - ky * 3;
        const u16* srow = in + ((size_t)(b * Wi + row_blk + ky) * Wi + kx) * ICP + ch * 32 + qq * 8;
#pragma unroll
        for (int i = 0; i < 4; ++i) {
            int c = wave * 4 + i;           // chunk 0..15: 1KB each
            int rh = c >> 3;                // staged row half (0/1)
            int pxb = (c & 7) * 16;         // px base of chunk
            const u16* src = srow + ((size_t)rh * Wi + pxb + pxl) * ICP;
            gload_lds16(src, &ldsA[pb][rh][pxb][0]);
        }
    };

    auto stageB = [&](int s, int pb) {
        int ch = s & (NCH - 1);
        int tap = s / NCH;
        if (wave < NOCT) {                  // NOCT 1KB chunks
            int slot = wave * 64 + lane;    // q*OCB + oc
            int q = slot / OCB, oc = slot % OCB;
            const u16* src = wp + (((size_t)(tap * NCH + ch) * 4 + q) * OC + ocg * OCB + oc) * 8;
            gload_lds16(src, &ldsB[pb][wave * 512]);
        }
    };

    f32x4 acc[4][NOCT];
#pragma unroll
    for (int mt = 0; mt < 4; ++mt)
#pragma unroll
        for (int ot = 0; ot < NOCT; ++ot)
            acc[mt][ot] = (f32x4){0.f, 0.f, 0.f, 0.f};

    stageA(0, 0);
    stageB(0, 0);
    __syncthreads();

    for (int s = 0; s < NS; ++s) {
        int pb = s & 1;
        if (s + 1 < NS) {                   // prefetch next step into back buffer
            stageA(s + 1, pb ^ 1);
            stageB(s + 1, pb ^ 1);
        }
        short8 afr[4], bfr[NOCT];
#pragma unroll
        for (int mt = 0; mt < 4; ++mt)
            afr[mt] = *(const short8*)&ldsA[pb][row_h][px0 + mt * 16 + l16][quad * 8];
#pragma unroll
        for (int ot = 0; ot < NOCT; ++ot)
            bfr[ot] = *(const short8*)&ldsB[pb][(quad * OCB + ot * 16 + l16) * 8];
#pragma unroll
        for (int mt = 0; mt < 4; ++mt)
#pragma unroll
            for (int ot = 0; ot < NOCT; ++ot)
                acc[mt][ot] = __builtin_amdgcn_mfma_f32_16x16x32_bf16(afr[mt], bfr[ot], acc[mt][ot], 0, 0, 0);
        __syncthreads();                    // drains vmcnt (staging) + lgkmcnt (reads)
    }

    float bv[NOCT];
#pragma unroll
    for (int ot = 0; ot < NOCT; ++ot) bv[ot] = bias[ocg * OCB + ot * 16 + l16];

#pragma unroll
    for (int mt = 0; mt < 4; ++mt) {
#pragma unroll
        for (int ot = 0; ot < NOCT; ++ot) {
#pragma unroll
            for (int r = 0; r < 4; ++r) {
                int px = px0 + mt * 16 + quad * 4 + r;
                float v = lrelu_f(acc[mt][ot][r] + bv[ot]);
                out[((size_t)(b * Wo + row_blk + row_h + PADOUT) * Wo + px + PADOUT) * OC + ocg * OCB + ot * 16 + l16] = f2bf(v);
            }
        }
    }
}

// ---------------- conv4: 5x5, 32->2, NHWC pad-2 in (132x132x32), + flow add -> NCHW f32 out
__global__ __launch_bounds__(256) void conv4_kernel(const u16* __restrict__ in, const float* __restrict__ w4p,
                                                    const float* __restrict__ b4, const float* __restrict__ flow,
                                                    float* __restrict__ out) {
    int gid = blockIdx.x * 256 + threadIdx.x;   // 16*128*128
    int x = gid & 127;
    int y = (gid >> 7) & 127;
    int b = gid >> 14;
    float acc0 = b4[0], acc1 = b4[1];
#pragma unroll
    for (int ky = 0; ky < 5; ++ky) {
#pragma unroll
        for (int kx = 0; kx < 5; ++kx) {
            const u16* p = in + ((size_t)(b * 132 + y + ky) * 132 + x + kx) * 32;
            const float* wb = w4p + (ky * 5 + kx) * 64;
#pragma unroll
            for (int g = 0; g < 4; ++g) {
                short8 vv = *(const short8*)(p + g * 8);
#pragma unroll
                for (int j = 0; j < 8; ++j) {
                    float v = bf2f((u16)vv[j]);
                    acc0 += v * wb[g * 8 + j];
                    acc1 += v * wb[32 + g * 8 + j];
                }
            }
        }
    }
    int o0 = ((b * 2 + 0) * HW + y) * HW + x;
    int o1 = o0 + HW * HW;
    out[o0] = acc0 + flow[o0];
    out[o1] = acc1 + flow[o1];
}

// ---------------- launch
extern "C" void kernel_launch(void* const* d_in, const int* in_sizes, int n_in,
                              void* d_out, int out_size, void* d_ws, size_t ws_size,
                              hipStream_t stream) {
    const float* ffirst  = (const float*)d_in[2];
    const float* fsecond = (const float*)d_in[3];
    const float* tflow   = (const float*)d_in[4];
    const float* wu      = (const float*)d_in[5];
    const float* w1 = (const float*)d_in[6];
    const float* b1 = (const float*)d_in[7];
    const float* w2 = (const float*)d_in[8];
    const float* b2 = (const float*)d_in[9];
    const float* w3 = (const float*)d_in[10];
    const float* b3 = (const float*)d_in[11];
    const float* w4 = (const float*)d_in[12];
    const float* b4 = (const float*)d_in[13];
    float* out = (float*)d_out;
    char* ws = (char*)d_ws;

    // packed weights
    u16* w1p = (u16*)(ws + 0);         // 147456 B
    u16* w2p = (u16*)(ws + 147456);    // 147456 B
    u16* w3p = (u16*)(ws + 294912);    // 36864 B
    float* w4p = (float*)(ws + 331776);// 6400 B

    float* flow = (float*)(ws + 602112);   // 2097152 B, ends 2699264
    u16* regA = (u16*)(ws + 2699264);      // feat2 59.3MB -> x1p 69.2MB -> x3p 17.8MB
    u16* regB = (u16*)(ws + 71921664);     // corr 34.6MB -> x2p 34.6MB; end 106532864

    // 1) weight packing
    pack_w<49, 64, 128><<<288, 256, 0, stream>>>(w1, w1p);
    pack_w<128, 128, 64><<<288, 256, 0, stream>>>(w2, w2p);
    pack_w<64, 64, 32><<<72, 256, 0, stream>>>(w3, w3p);
    pack_w4<<<7, 256, 0, stream>>>(w4, w4p);

    // 2) upflow -> flow (f32 NCHW)
    upflow_kernel<<<2048, 256, 0, stream>>>(tflow, wu, flow);

    // 3) warp -> feat2 fragment-native [16][134][12][144][8] bf16
    hipMemsetAsync(regA, 0, 59277312, stream);
    warp_kernel<<<12288, 256, 0, stream>>>(fsecond, flow, regA);

    // 4) correlation (banded MFMA) + lrelu -> corr NHWC (130,130,64) bf16
    hipMemsetAsync(regB, 0, 34611200, stream);
    corr_mfma<<<4096, 256, 0, stream>>>(ffirst, regA, regB);

    // 5) conv1 64->128 MFMA -> x1p NHWC pad1 (feat2 dead)
    hipMemsetAsync(regA, 0, 69222400, stream);
    conv_mfma<64, 128, 64, 1><<<2048, 256, 0, stream>>>(regB, w1p, b1, regA);

    // 6) conv2 128->64 MFMA -> x2p NHWC pad1 (corr dead)
    hipMemsetAsync(regB, 0, 34611200, stream);
    conv_mfma<128, 64, 64, 1><<<1024, 256, 0, stream>>>(regA, w2p, b2, regB);

    // 7) conv3 64->32 MFMA -> x3p NHWC pad2 (x1 dead)
    hipMemsetAsync(regA, 0, 17842176, stream);
    conv_mfma<64, 32, 32, 2><<<1024, 256, 0, stream>>>(regB, w3p, b3, regA);

    // 8) conv4 5x5 32->2 + flow add -> d_out (f32 NCHW)
    conv4_kernel<<<1024, 256, 0, stream>>>(regA, w4p, b4, flow, out);
}

// Round 2
// 625.281 us; speedup vs baseline: 1.0808x; 1.0485x over previous
//
#include <hip/hip_runtime.h>

typedef unsigned short u16;
typedef unsigned int u32;
typedef short short8 __attribute__((ext_vector_type(8)));
typedef float f32x4 __attribute__((ext_vector_type(4)));

#define HW 128

__device__ __forceinline__ float bf2f(u16 h) {
    u32 u = ((u32)h) << 16;
    return __uint_as_float(u);
}
__device__ __forceinline__ u16 f2bf(float f) {
    u32 u = __float_as_uint(f);
    u32 r = (u + 0x7FFFu + ((u >> 16) & 1u)) >> 16;
    return (u16)r;
}
__device__ __forceinline__ float lrelu_f(float v) {
    return v >= 0.f ? v : 0.1f * v;
}

// async global -> LDS, 16B per lane. LDS dest is WAVE-UNIFORM base; HW adds lane*16.
__device__ __forceinline__ void gload_lds16(const void* g, void* l) {
    __builtin_amdgcn_global_load_lds((const __attribute__((address_space(1))) void*)g,
                                     (__attribute__((address_space(3))) void*)l, 16, 0, 0);
}

// ---------------- weight pack for MFMA convs: [oc][ic][3][3] f32 -> [tap][ch][quad][oc][j8] bf16
template<int ICR, int ICP, int OC>
__global__ __launch_bounds__(256) void pack_w(const float* __restrict__ w, u16* __restrict__ dst) {
    constexpr int NCH = ICP / 32;
    constexpr int NTOT = 9 * NCH * 4 * OC * 8;
    int gid = blockIdx.x * 256 + threadIdx.x;
    if (gid >= NTOT) return;
    int j = gid & 7;
    int t = gid >> 3;
    int oc = t % OC; t /= OC;
    int quad = t & 3; t >>= 2;
    int ch = t % NCH;
    int tap = t / NCH;
    int ic = ch * 32 + quad * 8 + j;
    int ky = tap / 3, kx = tap % 3;
    float v = (ic < ICR) ? w[((oc * ICR + ic) * 3 + ky) * 3 + kx] : 0.f;
    dst[gid] = f2bf(v);
}

// ---------------- conv4 weight pack: [2][32][5][5] f32 -> [tap(25)][oc(2)][ic(32)] f32
__global__ __launch_bounds__(256) void pack_w4(const float* __restrict__ w, float* __restrict__ dst) {
    int gid = blockIdx.x * 256 + threadIdx.x;
    if (gid >= 1600) return;
    int ic = gid & 31;
    int t = gid >> 5;
    int oc = t & 1;
    int tap = t >> 1;
    dst[(tap * 2 + oc) * 32 + ic] = w[(oc * 32 + ic) * 25 + tap];
}

// ---------------- upflow: transposed conv, lhs_dilation=2, pad=2, k=4, groups=2
__global__ __launch_bounds__(256) void upflow_kernel(const float* __restrict__ tflow, const float* __restrict__ wu,
                                                     float* __restrict__ flow) {
    int gid = blockIdx.x * 256 + threadIdx.x;   // 524288 exact
    int x = gid & 127;
    int y = (gid >> 7) & 127;
    int c = (gid >> 14) & 1;
    int b = gid >> 15;
    float acc = 0.f;
#pragma unroll
    for (int ky = 0; ky < 4; ++ky) {
        int u = y + ky - 2;
        if ((u & 1) || u < 0 || u > 126) continue;
        int iy = u >> 1;
#pragma unroll
        for (int kx = 0; kx < 4; ++kx) {
            int v = x + kx - 2;
            if ((v & 1) || v < 0 || v > 126) continue;
            int ix = v >> 1;
            acc += tflow[((b * 2 + c) * 64 + iy) * 64 + ix] *
                   wu[c * 16 + (3 - ky) * 4 + (3 - kx)];
        }
    }
    flow[gid] = acc;
}

// ---------------- backward warp -> fragment-native bf16 feat2 [b][row 134][cg 12][x 144][8]
__global__ __launch_bounds__(256) void warp_kernel(const float* __restrict__ second, const float* __restrict__ flow,
                                                   u16* __restrict__ feat2) {
    int tid = threadIdx.x;
    int x = tid & 127;
    int half = tid >> 7;            // 0..1
    int blk = blockIdx.x;           // (b*128 + y)*6 + cgp
    int cgp = blk % 6;
    int t = blk / 6;
    int y = t & 127;
    int b = t >> 7;
    int cg = cgp * 2 + half;        // 0..11

    float fx = (float)x + 2.5f * flow[((b * 2 + 0) * HW + y) * HW + x];
    float fy = (float)y + 2.5f * flow[((b * 2 + 1) * HW + y) * HW + x];
    float x0f = floorf(fx), y0f = floorf(fy);
    int x0 = (int)x0f, y0 = (int)y0f;
    int x1 = x0 + 1, y1 = y0 + 1;
    float wx1 = fx - x0f, wx0 = (x0f + 1.f) - fx;
    float wy1 = fy - y0f, wy0 = (y0f + 1.f) - fy;
    float wA = wx0 * wy0, wB = wx1 * wy0, wC = wx0 * wy1, wD = wx1 * wy1;
    float vA = (x0 >= 0 && x0 <= 127 && y0 >= 0 && y0 <= 127) ? 1.f : 0.f;
    float vB = (x1 >= 0 && x1 <= 127 && y0 >= 0 && y0 <= 127) ? 1.f : 0.f;
    float vC = (x0 >= 0 && x0 <= 127 && y1 >= 0 && y1 <= 127) ? 1.f : 0.f;
    float vD = (x1 >= 0 && x1 <= 127 && y1 >= 0 && y1 <= 127) ? 1.f : 0.f;
    wA *= vA; wB *= vB; wC *= vC; wD *= vD;
    float ones = wA + wB + wC + wD;
    float maskf = (ones > 0.999f) ? 1.f : 0.f;
    wA *= maskf; wB *= maskf; wC *= maskf; wD *= maskf;
    int xc0 = min(max(x0, 0), 127), xc1 = min(max(x1, 0), 127);
    int yc0 = min(max(y0, 0), 127), yc1 = min(max(y1, 0), 127);
    int i00 = yc0 * HW + xc0, i01 = yc0 * HW + xc1;
    int i10 = yc1 * HW + xc0, i11 = yc1 * HW + xc1;

    const float* base = second + (size_t)b * 96 * HW * HW + (size_t)(cg * 8) * (HW * HW);
    short8 o;
#pragma unroll
    for (int j = 0; j < 8; ++j) {
        const float* pp = base + (size_t)j * (HW * HW);
        float v = wA * pp[i00] + wB * pp[i01] + wC * pp[i10] + wD * pp[i11];
        o[j] = (short)f2bf(v);
    }
    *(short8*)(feat2 + ((((size_t)(b * 134) + y + 3) * 12 + cg) * 144 + (x + 3)) * 8) = o;
}

// ---------------- correlation as banded MFMA GEMM -> NHWC (16,130,130,64) bf16 corr, + /96 + lrelu
__global__ __launch_bounds__(256) void corr_mfma(const float* __restrict__ first, const u16* __restrict__ feat2,
                                                 u16* __restrict__ corrp) {
    int tid = threadIdx.x;
    int wave = tid >> 6, lane = tid & 63;
    int quad = lane >> 4, l16 = lane & 15;
    int blk = blockIdx.x;            // 16 * 128 * 2 = 4096
    int half = blk & 1;
    int y = (blk >> 1) & 127;
    int b = blk >> 8;
    int x0 = (half * 4 + wave) * 16;

    short8 afr[3];
    const float* fbase = first + ((size_t)(b * 96) * HW + y) * HW + x0 + l16;
#pragma unroll
    for (int ch = 0; ch < 3; ++ch) {
        short8 a;
#pragma unroll
        for (int j = 0; j < 8; ++j)
            a[j] = (short)f2bf(fbase[(size_t)(ch * 32 + quad * 8 + j) * (HW * HW)]);
        afr[ch] = a;
    }

    f32x4 acc[7][2];
#pragma unroll
    for (int dy = 0; dy < 7; ++dy) {
        acc[dy][0] = (f32x4){0.f, 0.f, 0.f, 0.f};
        acc[dy][1] = (f32x4){0.f, 0.f, 0.f, 0.f};
    }

#pragma unroll
    for (int dy = 0; dy < 7; ++dy) {
#pragma unroll
        for (int ch = 0; ch < 3; ++ch) {
            const u16* rp = feat2 + ((((size_t)(b * 134) + y + dy) * 12 + ch * 4 + quad) * 144 + x0 + l16) * 8;
            short8 b0 = *(const short8*)(rp);
            short8 b1 = *(const short8*)(rp + 16 * 8);
            acc[dy][0] = __builtin_amdgcn_mfma_f32_16x16x32_bf16(afr[ch], b0, acc[dy][0], 0, 0, 0);
            acc[dy][1] = __builtin_amdgcn_mfma_f32_16x16x32_bf16(afr[ch], b1, acc[dy][1], 0, 0, 0);
        }
    }

    u16* op = corrp + ((size_t)(b * 130) + y + 1) * (130 * 64);
#pragma unroll
    for (int dy = 0; dy < 7; ++dy)
#pragma unroll
        for (int nt = 0; nt < 2; ++nt)
#pragma unroll
            for (int r = 0; r < 4; ++r) {
                int m = quad * 4 + r;
                int dx = nt * 16 + l16 - m;
                if (dx >= 0 && dx < 7) {
                    float v = lrelu_f(acc[dy][nt][r] * (1.f / 96.f));
                    op[(size_t)(x0 + m + 1) * 64 + dy * 7 + dx] = f2bf(v);
                }
            }
}

// ---------------- MFMA conv 3x3: stage-once-per-ch-group LDS structure.
// Block: 2 output rows x 128 px x OCB oc, 4 waves. K-loop over NCH ch-groups only;
// all 9 taps read the SAME staged LDS tile (4 rows x 144 px-slots x 32 ch, 36.9KB).
// LDS granule swizzle: within each 64B px-slot, ch-quad q lives at granule (q ^ (px>>1))&3
// -> wave b128 reads spread over 8 bank-quads (2-way, free). Staging is linear
// global_load_lds with the permutation folded into the per-lane SOURCE address.
// B fragments are direct global loads (weights 74-147KB, L2-resident across all blocks).
template<int ICP, int OC, int OCB, int PADOUT>
__global__ __launch_bounds__(256, 4) void conv_mfma(const u16* __restrict__ in, const u16* __restrict__ wp,
                                                    const float* __restrict__ bias, u16* __restrict__ out) {
    constexpr int NCH = ICP / 32;
    constexpr int NOCT = OCB / 16;
    constexpr int OCG = OC / OCB;
    constexpr int Wi = 130;
    constexpr int Wo = 128 + 2 * PADOUT;

    __shared__ __align__(16) u16 ldsA[4 * 144 * 32];   // [row 4][px 144][ch 32], granule-permuted

    int tid = threadIdx.x;
    int wave = tid >> 6, lane = tid & 63;
    int quad = lane >> 4, l16 = lane & 15;

    // bijective chunked XCD swizzle (gridDim % 8 == 0): each XCD gets a contiguous logical chunk
    int cpx = gridDim.x >> 3;
    int bid = blockIdx.x;
    int swz = (bid & 7) * cpx + (bid >> 3);
    int rowpair = swz & 63;
    int t = swz >> 6;
    int ocg = t % OCG;
    int b = t / OCG;
    int row_blk = rowpair * 2;
    int row_h = wave >> 1;          // wave's output row within the pair
    int px0 = (wave & 1) * 64;      // wave's 64-px half

    f32x4 acc[4][NOCT];
#pragma unroll
    for (int mt = 0; mt < 4; ++mt)
#pragma unroll
        for (int ot = 0; ot < NOCT; ++ot)
            acc[mt][ot] = (f32x4){0.f, 0.f, 0.f, 0.f};

    int pxl = lane >> 2;            // staging: lane -> px within 16-px chunk
    int g   = lane & 3;             // staging: lane -> granule within 64B slot

    for (int s = 0; s < NCH; ++s) {
        // ---- stage A: wave w stages input row row_blk+w, 9 chunks x 1KB (16 px-slots each)
        {
            const u16* rbase = in + ((size_t)(b * Wi + row_blk + wave) * Wi) * ICP + s * 32;
            u16* lbase = &ldsA[wave * (144 * 32)];
#pragma unroll
            for (int c = 0; c < 9; ++c) {
                int px = c * 16 + pxl;
                int q = (g ^ (px >> 1)) & 3;       // which ch-quad this granule holds
                int pxg = px > 129 ? 129 : px;     // clamp pad slots to valid memory
                const u16* src = rbase + (size_t)pxg * ICP + q * 8;
                gload_lds16(src, lbase + c * 16 * 32);
            }
        }
        __syncthreads();   // drains vmcnt: staged tile visible to all waves

        // ---- compute: 9 taps from LDS, B from global (L2-hot)
#pragma unroll
        for (int ky = 0; ky < 3; ++ky) {
#pragma unroll
            for (int kx = 0; kx < 3; ++kx) {
                const u16* bptr = wp + ((((size_t)(ky * 3 + kx) * NCH + s) * 4 + quad) * OC + ocg * OCB + l16) * 8;
                short8 bfr[NOCT];
#pragma unroll
                for (int ot = 0; ot < NOCT; ++ot)
                    bfr[ot] = *(const short8*)(bptr + ot * 16 * 8);
                short8 afr[4];
#pragma unroll
                for (int mt = 0; mt < 4; ++mt) {
                    int rpx = px0 + kx + mt * 16 + l16;
                    int gg = (quad ^ (rpx >> 1)) & 3;
                    afr[mt] = *(const short8*)&ldsA[((row_h + ky) * 144 + rpx) * 32 + gg * 8];
                }
#pragma unroll
                for (int mt = 0; mt < 4; ++mt)
#pragma unroll
                    for (int ot = 0; ot < NOCT; ++ot)
                        acc[mt][ot] = __builtin_amdgcn_mfma_f32_16x16x32_bf16(afr[mt], bfr[ot], acc[mt][ot], 0, 0, 0);
            }
        }
        __syncthreads();   // protect LDS tile until all waves finished reading
    }

    float bv[NOCT];
#pragma unroll
    for (int ot = 0; ot < NOCT; ++ot) bv[ot] = bias[ocg * OCB + ot * 16 + l16];

#pragma unroll
    for (int mt = 0; mt < 4; ++mt) {
#pragma unroll
        for (int ot = 0; ot < NOCT; ++ot) {
#pragma unroll
            for (int r = 0; r < 4; ++r) {
                int px = px0 + mt * 16 + quad * 4 + r;
                float v = lrelu_f(acc[mt][ot][r] + bv[ot]);
                out[((size_t)(b * Wo + row_blk + row_h + PADOUT) * Wo + px + PADOUT) * OC + ocg * OCB + ot * 16 + l16] = f2bf(v);
            }
        }
    }
}

// ---------------- conv4: 5x5, 32->2, NHWC pad-2 in (132x132x32), + flow add -> NCHW f32 out
__global__ __launch_bounds__(256) void conv4_kernel(const u16* __restrict__ in, const float* __restrict__ w4p,
                                                    const float* __restrict__ b4, const float* __restrict__ flow,
                                                    float* __restrict__ out) {
    int gid = blockIdx.x * 256 + threadIdx.x;   // 16*128*128
    int x = gid & 127;
    int y = (gid >> 7) & 127;
    int b = gid >> 14;
    float acc0 = b4[0], acc1 = b4[1];
#pragma unroll
    for (int ky = 0; ky < 5; ++ky) {
#pragma unroll
        for (int kx = 0; kx < 5; ++kx) {
            const u16* p = in + ((size_t)(b * 132 + y + ky) * 132 + x + kx) * 32;
            const float* wb = w4p + (ky * 5 + kx) * 64;
#pragma unroll
            for (int g = 0; g < 4; ++g) {
                short8 vv = *(const short8*)(p + g * 8);
#pragma unroll
                for (int j = 0; j < 8; ++j) {
                    float v = bf2f((u16)vv[j]);
                    acc0 += v * wb[g * 8 + j];
                    acc1 += v * wb[32 + g * 8 + j];
                }
            }
        }
    }
    int o0 = ((b * 2 + 0) * HW + y) * HW + x;
    int o1 = o0 + HW * HW;
    out[o0] = acc0 + flow[o0];
    out[o1] = acc1 + flow[o1];
}

// ---------------- launch
extern "C" void kernel_launch(void* const* d_in, const int* in_sizes, int n_in,
                              void* d_out, int out_size, void* d_ws, size_t ws_size,
                              hipStream_t stream) {
    const float* ffirst  = (const float*)d_in[2];
    const float* fsecond = (const float*)d_in[3];
    const float* tflow   = (const float*)d_in[4];
    const float* wu      = (const float*)d_in[5];
    const float* w1 = (const float*)d_in[6];
    const float* b1 = (const float*)d_in[7];
    const float* w2 = (const float*)d_in[8];
    const float* b2 = (const float*)d_in[9];
    const float* w3 = (const float*)d_in[10];
    const float* b3 = (const float*)d_in[11];
    const float* w4 = (const float*)d_in[12];
    const float* b4 = (const float*)d_in[13];
    float* out = (float*)d_out;
    char* ws = (char*)d_ws;

    // packed weights
    u16* w1p = (u16*)(ws + 0);         // 147456 B
    u16* w2p = (u16*)(ws + 147456);    // 147456 B
    u16* w3p = (u16*)(ws + 294912);    // 36864 B
    float* w4p = (float*)(ws + 331776);// 6400 B

    float* flow = (float*)(ws + 602112);   // 2097152 B, ends 2699264
    u16* regA = (u16*)(ws + 2699264);      // feat2 59.3MB -> x1p 69.2MB -> x3p 17.8MB
    u16* regB = (u16*)(ws + 71921664);     // corr 34.6MB -> x2p 34.6MB; end 106532864

    // 1) weight packing
    pack_w<49, 64, 128><<<288, 256, 0, stream>>>(w1, w1p);
    pack_w<128, 128, 64><<<288, 256, 0, stream>>>(w2, w2p);
    pack_w<64, 64, 32><<<72, 256, 0, stream>>>(w3, w3p);
    pack_w4<<<7, 256, 0, stream>>>(w4, w4p);

    // 2) upflow -> flow (f32 NCHW)
    upflow_kernel<<<2048, 256, 0, stream>>>(tflow, wu, flow);

    // 3) warp -> feat2 fragment-native [16][134][12][144][8] bf16
    hipMemsetAsync(regA, 0, 59277312, stream);
    warp_kernel<<<12288, 256, 0, stream>>>(fsecond, flow, regA);

    // 4) correlation (banded MFMA) + lrelu -> corr NHWC (130,130,64) bf16
    hipMemsetAsync(regB, 0, 34611200, stream);
    corr_mfma<<<4096, 256, 0, stream>>>(ffirst, regA, regB);

    // 5) conv1 64->128 MFMA -> x1p NHWC pad1 (feat2 dead)
    hipMemsetAsync(regA, 0, 69222400, stream);
    conv_mfma<64, 128, 64, 1><<<2048, 256, 0, stream>>>(regB, w1p, b1, regA);

    // 6) conv2 128->64 MFMA -> x2p NHWC pad1 (corr dead)
    hipMemsetAsync(regB, 0, 34611200, stream);
    conv_mfma<128, 64, 64, 1><<<1024, 256, 0, stream>>>(regA, w2p, b2, regB);

    // 7) conv3 64->32 MFMA -> x3p NHWC pad2 (x1 dead)
    hipMemsetAsync(regA, 0, 17842176, stream);
    conv_mfma<64, 32, 32, 2><<<1024, 256, 0, stream>>>(regB, w3p, b3, regA);

    // 8) conv4 5x5 32->2 + flow add -> d_out (f32 NCHW)
    conv4_kernel<<<1024, 256, 0, stream>>>(regA, w4p, b4, flow, out);
}

// Round 3
// 558.541 us; speedup vs baseline: 1.2099x; 1.1195x over previous
//
#include <hip/hip_runtime.h>

typedef unsigned short u16;
typedef unsigned int u32;
typedef short short8 __attribute__((ext_vector_type(8)));
typedef float f32x4 __attribute__((ext_vector_type(4)));

#define HW 128

__device__ __forceinline__ float bf2f(u16 h) {
    u32 u = ((u32)h) << 16;
    return __uint_as_float(u);
}
__device__ __forceinline__ u16 f2bf(float f) {
    u32 u = __float_as_uint(f);
    u32 r = (u + 0x7FFFu + ((u >> 16) & 1u)) >> 16;
    return (u16)r;
}
__device__ __forceinline__ float lrelu_f(float v) {
    return v >= 0.f ? v : 0.1f * v;
}

// async global -> LDS, 16B per lane. LDS dest is WAVE-UNIFORM base; HW adds lane*16.
__device__ __forceinline__ void gload_lds16(const void* g, void* l) {
    __builtin_amdgcn_global_load_lds((const __attribute__((address_space(1))) void*)g,
                                     (__attribute__((address_space(3))) void*)l, 16, 0, 0);
}

// ---------------- weight pack for MFMA convs: [oc][ic][3][3] f32 -> [tap][ch][quad][oc][j8] bf16
template<int ICR, int ICP, int OC>
__global__ __launch_bounds__(256) void pack_w(const float* __restrict__ w, u16* __restrict__ dst) {
    constexpr int NCH = ICP / 32;
    constexpr int NTOT = 9 * NCH * 4 * OC * 8;
    int gid = blockIdx.x * 256 + threadIdx.x;
    if (gid >= NTOT) return;
    int j = gid & 7;
    int t = gid >> 3;
    int oc = t % OC; t /= OC;
    int quad = t & 3; t >>= 2;
    int ch = t % NCH;
    int tap = t / NCH;
    int ic = ch * 32 + quad * 8 + j;
    int ky = tap / 3, kx = tap % 3;
    float v = (ic < ICR) ? w[((oc * ICR + ic) * 3 + ky) * 3 + kx] : 0.f;
    dst[gid] = f2bf(v);
}

// ---------------- conv4 weight pack: [2][32][5][5] f32 -> [tap(25)][oc(2)][ic(32)] f32
__global__ __launch_bounds__(256) void pack_w4(const float* __restrict__ w, float* __restrict__ dst) {
    int gid = blockIdx.x * 256 + threadIdx.x;
    if (gid >= 1600) return;
    int ic = gid & 31;
    int t = gid >> 5;
    int oc = t & 1;
    int tap = t >> 1;
    dst[(tap * 2 + oc) * 32 + ic] = w[(oc * 32 + ic) * 25 + tap];
}

// ---------------- border zeroing: NHWC buffer [16][S][S][C], interior [LO,LO+NI) x [LO,LO+NI)
template<int S, int LO, int NI, int C>
__global__ __launch_bounds__(256) void zero_border(u16* __restrict__ buf) {
    constexpr int MID = S - NI;                 // border cols per interior row
    constexpr int NB = S * S - NI * NI;         // border px per image
    constexpr int TOP = LO * S;
    int idx = blockIdx.x * 256 + threadIdx.x;
    if (idx >= 16 * NB) return;
    int b = idx / NB;
    int r = idx - b * NB;
    int y, x;
    if (r < TOP) { y = r / S; x = r - y * S; }
    else if (r < TOP + NI * MID) {
        int rr = r - TOP;
        y = LO + rr / MID;
        int c0 = rr - (rr / MID) * MID;
        x = c0 < LO ? c0 : c0 + NI;
    } else {
        int rr = r - TOP - NI * MID;
        y = LO + NI + rr / S;
        x = rr - (rr / S) * S;
    }
    u16* p = buf + ((size_t)(b * S + y) * S + x) * C;
#pragma unroll
    for (int c = 0; c < C; c += 8)
        *(short8*)(p + c) = (short8){0, 0, 0, 0, 0, 0, 0, 0};
}

// ---------------- feat2 halo zeroing: layout [16][134][12][144][8]
// rows 0..2 & 131..133 full; rows 3..130 cols {0..2, 131..143}
__global__ __launch_bounds__(256) void zero_feat2_halo(u16* __restrict__ f) {
    constexpr int FULLROWS = 6 * 12 * 144;      // 10368 slots
    constexpr int PER_B = FULLROWS + 128 * 12 * 16;  // 34944 slots
    int idx = blockIdx.x * 256 + threadIdx.x;
    if (idx >= 16 * PER_B) return;
    int b = idx / PER_B;
    int r = idx - b * PER_B;
    int row, cg, x;
    if (r < FULLROWS) {
        x = r % 144; int t = r / 144;
        cg = t % 12; int k = t / 12;            // 0..5
        row = k < 3 ? k : 128 + k;              // 0,1,2,131,132,133
    } else {
        int rr = r - FULLROWS;
        int c0 = rr & 15; int t = rr >> 4;
        cg = t % 12; row = 3 + t / 12;          // 3..130
        x = c0 < 3 ? c0 : c0 + 128;             // 0..2, 131..143
    }
    *(short8*)(f + ((((size_t)(b * 134) + row) * 12 + cg) * 144 + x) * 8) =
        (short8){0, 0, 0, 0, 0, 0, 0, 0};
}

// ---------------- upflow: transposed conv, lhs_dilation=2, pad=2, k=4, groups=2
__global__ __launch_bounds__(256) void upflow_kernel(const float* __restrict__ tflow, const float* __restrict__ wu,
                                                     float* __restrict__ flow) {
    int gid = blockIdx.x * 256 + threadIdx.x;   // 524288 exact
    int x = gid & 127;
    int y = (gid >> 7) & 127;
    int c = (gid >> 14) & 1;
    int b = gid >> 15;
    float acc = 0.f;
#pragma unroll
    for (int ky = 0; ky < 4; ++ky) {
        int u = y + ky - 2;
        if ((u & 1) || u < 0 || u > 126) continue;
        int iy = u >> 1;
#pragma unroll
        for (int kx = 0; kx < 4; ++kx) {
            int v = x + kx - 2;
            if ((v & 1) || v < 0 || v > 126) continue;
            int ix = v >> 1;
            acc += tflow[((b * 2 + c) * 64 + iy) * 64 + ix] *
                   wu[c * 16 + (3 - ky) * 4 + (3 - kx)];
        }
    }
    flow[gid] = acc;
}

// ---------------- backward warp -> fragment-native bf16 feat2 [b][row 134][cg 12][x 144][8]
__global__ __launch_bounds__(256) void warp_kernel(const float* __restrict__ second, const float* __restrict__ flow,
                                                   u16* __restrict__ feat2) {
    int tid = threadIdx.x;
    int x = tid & 127;
    int half = tid >> 7;            // 0..1
    int blk = blockIdx.x;           // (b*128 + y)*6 + cgp
    int cgp = blk % 6;
    int t = blk / 6;
    int y = t & 127;
    int b = t >> 7;
    int cg = cgp * 2 + half;        // 0..11

    float fx = (float)x + 2.5f * flow[((b * 2 + 0) * HW + y) * HW + x];
    float fy = (float)y + 2.5f * flow[((b * 2 + 1) * HW + y) * HW + x];
    float x0f = floorf(fx), y0f = floorf(fy);
    int x0 = (int)x0f, y0 = (int)y0f;
    int x1 = x0 + 1, y1 = y0 + 1;
    float wx1 = fx - x0f, wx0 = (x0f + 1.f) - fx;
    float wy1 = fy - y0f, wy0 = (y0f + 1.f) - fy;
    float wA = wx0 * wy0, wB = wx1 * wy0, wC = wx0 * wy1, wD = wx1 * wy1;
    float vA = (x0 >= 0 && x0 <= 127 && y0 >= 0 && y0 <= 127) ? 1.f : 0.f;
    float vB = (x1 >= 0 && x1 <= 127 && y0 >= 0 && y0 <= 127) ? 1.f : 0.f;
    float vC = (x0 >= 0 && x0 <= 127 && y1 >= 0 && y1 <= 127) ? 1.f : 0.f;
    float vD = (x1 >= 0 && x1 <= 127 && y1 >= 0 && y1 <= 127) ? 1.f : 0.f;
    wA *= vA; wB *= vB; wC *= vC; wD *= vD;
    float ones = wA + wB + wC + wD;
    float maskf = (ones > 0.999f) ? 1.f : 0.f;
    wA *= maskf; wB *= maskf; wC *= maskf; wD *= maskf;
    int xc0 = min(max(x0, 0), 127), xc1 = min(max(x1, 0), 127);
    int yc0 = min(max(y0, 0), 127), yc1 = min(max(y1, 0), 127);
    int i00 = yc0 * HW + xc0, i01 = yc0 * HW + xc1;
    int i10 = yc1 * HW + xc0, i11 = yc1 * HW + xc1;

    const float* base = second + (size_t)b * 96 * HW * HW + (size_t)(cg * 8) * (HW * HW);
    short8 o;
#pragma unroll
    for (int j = 0; j < 8; ++j) {
        const float* pp = base + (size_t)j * (HW * HW);
        float v = wA * pp[i00] + wB * pp[i01] + wC * pp[i10] + wD * pp[i11];
        o[j] = (short)f2bf(v);
    }
    *(short8*)(feat2 + ((((size_t)(b * 134) + y + 3) * 12 + cg) * 144 + (x + 3)) * 8) = o;
}

// ---------------- correlation as banded MFMA GEMM -> NHWC (16,130,130,64) bf16 corr, + /96 + lrelu
// also zeroes pad channels 49..63 of its interior rows (buffer is not pre-memset).
__global__ __launch_bounds__(256) void corr_mfma(const float* __restrict__ first, const u16* __restrict__ feat2,
                                                 u16* __restrict__ corrp) {
    int tid = threadIdx.x;
    int wave = tid >> 6, lane = tid & 63;
    int quad = lane >> 4, l16 = lane & 15;
    int blk = blockIdx.x;            // 16 * 128 * 2 = 4096
    int half = blk & 1;
    int y = (blk >> 1) & 127;
    int b = blk >> 8;
    int x0 = (half * 4 + wave) * 16;

    short8 afr[3];
    const float* fbase = first + ((size_t)(b * 96) * HW + y) * HW + x0 + l16;
#pragma unroll
    for (int ch = 0; ch < 3; ++ch) {
        short8 a;
#pragma unroll
        for (int j = 0; j < 8; ++j)
            a[j] = (short)f2bf(fbase[(size_t)(ch * 32 + quad * 8 + j) * (HW * HW)]);
        afr[ch] = a;
    }

    f32x4 acc[7][2];
#pragma unroll
    for (int dy = 0; dy < 7; ++dy) {
        acc[dy][0] = (f32x4){0.f, 0.f, 0.f, 0.f};
        acc[dy][1] = (f32x4){0.f, 0.f, 0.f, 0.f};
    }

#pragma unroll
    for (int dy = 0; dy < 7; ++dy) {
#pragma unroll
        for (int ch = 0; ch < 3; ++ch) {
            const u16* rp = feat2 + ((((size_t)(b * 134) + y + dy) * 12 + ch * 4 + quad) * 144 + x0 + l16) * 8;
            short8 b0 = *(const short8*)(rp);
            short8 b1 = *(const short8*)(rp + 16 * 8);
            acc[dy][0] = __builtin_amdgcn_mfma_f32_16x16x32_bf16(afr[ch], b0, acc[dy][0], 0, 0, 0);
            acc[dy][1] = __builtin_amdgcn_mfma_f32_16x16x32_bf16(afr[ch], b1, acc[dy][1], 0, 0, 0);
        }
    }

    u16* op = corrp + ((size_t)(b * 130) + y + 1) * (130 * 64);
#pragma unroll
    for (int dy = 0; dy < 7; ++dy)
#pragma unroll
        for (int nt = 0; nt < 2; ++nt)
#pragma unroll
            for (int r = 0; r < 4; ++r) {
                int m = quad * 4 + r;
                int dx = nt * 16 + l16 - m;
                if (dx >= 0 && dx < 7) {
                    float v = lrelu_f(acc[dy][nt][r] * (1.f / 96.f));
                    op[(size_t)(x0 + m + 1) * 64 + dy * 7 + dx] = f2bf(v);
                }
            }

    // pad channels 49..63 must be zero (weights for ic>=49 are zero, but memory may be NaN)
    if (l16 < 15) {
#pragma unroll
        for (int r = 0; r < 4; ++r) {
            int m = quad * 4 + r;
            op[(size_t)(x0 + m + 1) * 64 + 49 + l16] = 0;
        }
    }
}

// ---------------- MFMA conv 3x3: stage-once-per-ch-group + 2-phase double-buffered LDS.
// Block: 2 output rows x 128 px x OCB oc, 4 waves. K-loop over NCH ch-groups;
// all 9 taps read the staged LDS tile (4 rows x 144 px-slots x 32 ch, 36.9KB/buf).
// Per step: ISSUE async stage of step s+1 into back buffer FIRST, then compute step s
// from front buffer, then one __syncthreads() (drains vmcnt+lgkm) -> T3-minimum overlap.
// Granule swizzle: within each 64B px-slot, ch-quad q lives at granule (q ^ (px>>1))&3
// (bank-conflict-free ds_read_b128, verified 0 conflicts). Staging stays linear
// global_load_lds with the permutation folded into the per-lane SOURCE address.
template<int ICP, int OC, int OCB, int PADOUT>
__global__ __launch_bounds__(256, 2) void conv_mfma(const u16* __restrict__ in, const u16* __restrict__ wp,
                                                    const float* __restrict__ bias, u16* __restrict__ out) {
    constexpr int NCH = ICP / 32;
    constexpr int NOCT = OCB / 16;
    constexpr int OCG = OC / OCB;
    constexpr int Wi = 130;
    constexpr int Wo = 128 + 2 * PADOUT;

    __shared__ __align__(16) u16 ldsA[2][4 * 144 * 32];   // double-buffered, granule-permuted

    int tid = threadIdx.x;
    int wave = tid >> 6, lane = tid & 63;
    int quad = lane >> 4, l16 = lane & 15;

    // bijective chunked XCD swizzle (gridDim % 8 == 0)
    int cpx = gridDim.x >> 3;
    int bid = blockIdx.x;
    int swz = (bid & 7) * cpx + (bid >> 3);
    int rowpair = swz & 63;
    int t = swz >> 6;
    int ocg = t % OCG;
    int b = t / OCG;
    int row_blk = rowpair * 2;
    int row_h = wave >> 1;          // wave's output row within the pair
    int px0 = (wave & 1) * 64;      // wave's 64-px half

    int pxl = lane >> 2;            // staging: lane -> px within 16-px chunk
    int g   = lane & 3;             // staging: lane -> granule within 64B slot

    auto stageA = [&](int s) {
        const u16* rbase = in + ((size_t)(b * Wi + row_blk + wave) * Wi) * ICP + s * 32;
        u16* lbase = &ldsA[s & 1][wave * (144 * 32)];
#pragma unroll
        for (int c = 0; c < 9; ++c) {
            int px = c * 16 + pxl;
            int q = (g ^ (px >> 1)) & 3;       // which ch-quad this granule holds
            int pxg = px > 129 ? 129 : px;     // clamp pad slots to valid memory
            gload_lds16(rbase + (size_t)pxg * ICP + q * 8, lbase + c * 16 * 32);
        }
    };

    f32x4 acc[4][NOCT];
#pragma unroll
    for (int mt = 0; mt < 4; ++mt)
#pragma unroll
        for (int ot = 0; ot < NOCT; ++ot)
            acc[mt][ot] = (f32x4){0.f, 0.f, 0.f, 0.f};

    stageA(0);
    __syncthreads();

    for (int s = 0; s < NCH; ++s) {
        if (s + 1 < NCH) stageA(s + 1);        // async prefetch FIRST, hides under MFMAs
        const u16* lA = &ldsA[s & 1][0];
#pragma unroll
        for (int ky = 0; ky < 3; ++ky) {
#pragma unroll
            for (int kx = 0; kx < 3; ++kx) {
                const u16* bptr = wp + ((((size_t)(ky * 3 + kx) * NCH + s) * 4 + quad) * OC + ocg * OCB + l16) * 8;
                short8 bfr[NOCT];
#pragma unroll
                for (int ot = 0; ot < NOCT; ++ot)
                    bfr[ot] = *(const short8*)(bptr + ot * 16 * 8);
                short8 afr[4];
#pragma unroll
                for (int mt = 0; mt < 4; ++mt) {
                    int rpx = px0 + kx + mt * 16 + l16;
                    int gg = (quad ^ (rpx >> 1)) & 3;
                    afr[mt] = *(const short8*)&lA[((row_h + ky) * 144 + rpx) * 32 + gg * 8];
                }
#pragma unroll
                for (int mt = 0; mt < 4; ++mt)
#pragma unroll
                    for (int ot = 0; ot < NOCT; ++ot)
                        acc[mt][ot] = __builtin_amdgcn_mfma_f32_16x16x32_bf16(afr[mt], bfr[ot], acc[mt][ot], 0, 0, 0);
            }
        }
        __syncthreads();   // front buffer fully read; prefetch (vmcnt) drained
    }

    float bv[NOCT];
#pragma unroll
    for (int ot = 0; ot < NOCT; ++ot) bv[ot] = bias[ocg * OCB + ot * 16 + l16];

#pragma unroll
    for (int mt = 0; mt < 4; ++mt) {
#pragma unroll
        for (int ot = 0; ot < NOCT; ++ot) {
#pragma unroll
            for (int r = 0; r < 4; ++r) {
                int px = px0 + mt * 16 + quad * 4 + r;
                float v = lrelu_f(acc[mt][ot][r] + bv[ot]);
                out[((size_t)(b * Wo + row_blk + row_h + PADOUT) * Wo + px + PADOUT) * OC + ocg * OCB + ot * 16 + l16] = f2bf(v);
            }
        }
    }
}

// ---------------- conv4: 5x5, 32->2, NHWC pad-2 in (132x132x32), + flow add -> NCHW f32 out
__global__ __launch_bounds__(256) void conv4_kernel(const u16* __restrict__ in, const float* __restrict__ w4p,
                                                    const float* __restrict__ b4, const float* __restrict__ flow,
                                                    float* __restrict__ out) {
    int gid = blockIdx.x * 256 + threadIdx.x;   // 16*128*128
    int x = gid & 127;
    int y = (gid >> 7) & 127;
    int b = gid >> 14;
    float acc0 = b4[0], acc1 = b4[1];
#pragma unroll
    for (int ky = 0; ky < 5; ++ky) {
#pragma unroll
        for (int kx = 0; kx < 5; ++kx) {
            const u16* p = in + ((size_t)(b * 132 + y + ky) * 132 + x + kx) * 32;
            const float* wb = w4p + (ky * 5 + kx) * 64;
#pragma unroll
            for (int g = 0; g < 4; ++g) {
                short8 vv = *(const short8*)(p + g * 8);
#pragma unroll
                for (int j = 0; j < 8; ++j) {
                    float v = bf2f((u16)vv[j]);
                    acc0 += v * wb[g * 8 + j];
                    acc1 += v * wb[32 + g * 8 + j];
                }
            }
        }
    }
    int o0 = ((b * 2 + 0) * HW + y) * HW + x;
    int o1 = o0 + HW * HW;
    out[o0] = acc0 + flow[o0];
    out[o1] = acc1 + flow[o1];
}

// ---------------- launch
extern "C" void kernel_launch(void* const* d_in, const int* in_sizes, int n_in,
                              void* d_out, int out_size, void* d_ws, size_t ws_size,
                              hipStream_t stream) {
    const float* ffirst  = (const float*)d_in[2];
    const float* fsecond = (const float*)d_in[3];
    const float* tflow   = (const float*)d_in[4];
    const float* wu      = (const float*)d_in[5];
    const float* w1 = (const float*)d_in[6];
    const float* b1 = (const float*)d_in[7];
    const float* w2 = (const float*)d_in[8];
    const float* b2 = (const float*)d_in[9];
    const float* w3 = (const float*)d_in[10];
    const float* b3 = (const float*)d_in[11];
    const float* w4 = (const float*)d_in[12];
    const float* b4 = (const float*)d_in[13];
    float* out = (float*)d_out;
    char* ws = (char*)d_ws;

    // packed weights
    u16* w1p = (u16*)(ws + 0);         // 147456 B
    u16* w2p = (u16*)(ws + 147456);    // 147456 B
    u16* w3p = (u16*)(ws + 294912);    // 36864 B
    float* w4p = (float*)(ws + 331776);// 6400 B

    float* flow = (float*)(ws + 602112);   // 2097152 B, ends 2699264
    u16* regA = (u16*)(ws + 2699264);      // feat2 59.3MB -> x1p 69.2MB -> x3p 17.8MB
    u16* regB = (u16*)(ws + 71921664);     // corr 34.6MB -> x2p 34.6MB; end 106532864

    // 1) weight packing
    pack_w<49, 64, 128><<<288, 256, 0, stream>>>(w1, w1p);
    pack_w<128, 128, 64><<<288, 256, 0, stream>>>(w2, w2p);
    pack_w<64, 64, 32><<<72, 256, 0, stream>>>(w3, w3p);
    pack_w4<<<7, 256, 0, stream>>>(w4, w4p);

    // 2) upflow -> flow (f32 NCHW)
    upflow_kernel<<<2048, 256, 0, stream>>>(tflow, wu, flow);

    // 3) warp -> feat2 fragment-native [16][134][12][144][8] bf16 (halo zeroed, no full memset)
    zero_feat2_halo<<<2184, 256, 0, stream>>>(regA);
    warp_kernel<<<12288, 256, 0, stream>>>(fsecond, flow, regA);

    // 4) correlation (banded MFMA) + lrelu -> corr NHWC (130,130,64) bf16
    zero_border<130, 1, 128, 64><<<33, 256, 0, stream>>>(regB);
    corr_mfma<<<4096, 256, 0, stream>>>(ffirst, regA, regB);

    // 5) conv1 64->128 MFMA -> x1p NHWC pad1 (feat2 dead after corr; zero x1p border only)
    zero_border<130, 1, 128, 128><<<33, 256, 0, stream>>>(regA);
    conv_mfma<64, 128, 64, 1><<<2048, 256, 0, stream>>>(regB, w1p, b1, regA);

    // 6) conv2 128->64 MFMA -> x2p NHWC pad1 (corr dead after conv1)
    zero_border<130, 1, 128, 64><<<33, 256, 0, stream>>>(regB);
    conv_mfma<128, 64, 64, 1><<<1024, 256, 0, stream>>>(regA, w2p, b2, regB);

    // 7) conv3 64->32 MFMA -> x3p NHWC pad2 (x1 dead after conv2)
    zero_border<132, 2, 128, 32><<<65, 256, 0, stream>>>(regA);
    conv_mfma<64, 32, 32, 2><<<1024, 256, 0, stream>>>(regB, w3p, b3, regA);

    // 8) conv4 5x5 32->2 + flow add -> d_out (f32 NCHW)
    conv4_kernel<<<1024, 256, 0, stream>>>(regA, w4p, b4, flow, out);
}

// Round 5
// 538.336 us; speedup vs baseline: 1.2554x; 1.0375x over previous
//
#include <hip/hip_runtime.h>

typedef unsigned short u16;
typedef unsigned int u32;
typedef short short8 __attribute__((ext_vector_type(8)));
typedef float f32x4 __attribute__((ext_vector_type(4)));

#define HW 128

__device__ __forceinline__ float bf2f(u16 h) {
    u32 u = ((u32)h) << 16;
    return __uint_as_float(u);
}
__device__ __forceinline__ u16 f2bf(float f) {
    u32 u = __float_as_uint(f);
    u32 r = (u + 0x7FFFu + ((u >> 16) & 1u)) >> 16;
    return (u16)r;
}
__device__ __forceinline__ float lrelu_f(float v) {
    return v >= 0.f ? v : 0.1f * v;
}

// async global -> LDS, 16B per lane. LDS dest is WAVE-UNIFORM base; HW adds lane*16.
__device__ __forceinline__ void gload_lds16(const void* g, void* l) {
    __builtin_amdgcn_global_load_lds((const __attribute__((address_space(1))) void*)g,
                                     (__attribute__((address_space(3))) void*)l, 16, 0, 0);
}

// ---------------- weight pack for MFMA convs: [oc][ic][3][3] f32 -> [tap][ch][quad][oc][j8] bf16
template<int ICR, int ICP, int OC>
__global__ __launch_bounds__(256) void pack_w(const float* __restrict__ w, u16* __restrict__ dst) {
    constexpr int NCH = ICP / 32;
    constexpr int NTOT = 9 * NCH * 4 * OC * 8;
    int gid = blockIdx.x * 256 + threadIdx.x;
    if (gid >= NTOT) return;
    int j = gid & 7;
    int t = gid >> 3;
    int oc = t % OC; t /= OC;
    int quad = t & 3; t >>= 2;
    int ch = t % NCH;
    int tap = t / NCH;
    int ic = ch * 32 + quad * 8 + j;
    int ky = tap / 3, kx = tap % 3;
    float v = (ic < ICR) ? w[((oc * ICR + ic) * 3 + ky) * 3 + kx] : 0.f;
    dst[gid] = f2bf(v);
}

// ---------------- conv4 weight pack: [2][32][5][5] f32 -> [tap(25)][oc(2)][ic(32)] f32
__global__ __launch_bounds__(256) void pack_w4(const float* __restrict__ w, float* __restrict__ dst) {
    int gid = blockIdx.x * 256 + threadIdx.x;
    if (gid >= 1600) return;
    int ic = gid & 31;
    int t = gid >> 5;
    int oc = t & 1;
    int tap = t >> 1;
    dst[(tap * 2 + oc) * 32 + ic] = w[(oc * 32 + ic) * 25 + tap];
}

// ---------------- border zeroing: NHWC buffer [16][S][S][C], interior [LO,LO+NI) x [LO,LO+NI)
template<int S, int LO, int NI, int C>
__global__ __launch_bounds__(256) void zero_border(u16* __restrict__ buf) {
    constexpr int MID = S - NI;                 // border cols per interior row
    constexpr int NB = S * S - NI * NI;         // border px per image
    constexpr int TOP = LO * S;
    int idx = blockIdx.x * 256 + threadIdx.x;
    if (idx >= 16 * NB) return;
    int b = idx / NB;
    int r = idx - b * NB;
    int y, x;
    if (r < TOP) { y = r / S; x = r - y * S; }
    else if (r < TOP + NI * MID) {
        int rr = r - TOP;
        y = LO + rr / MID;
        int c0 = rr - (rr / MID) * MID;
        x = c0 < LO ? c0 : c0 + NI;
    } else {
        int rr = r - TOP - NI * MID;
        y = LO + NI + rr / S;
        x = rr - (rr / S) * S;
    }
    u16* p = buf + ((size_t)(b * S + y) * S + x) * C;
#pragma unroll
    for (int c = 0; c < C; c += 8)
        *(short8*)(p + c) = (short8){0, 0, 0, 0, 0, 0, 0, 0};
}

// ---------------- feat2 halo zeroing: layout [16][134][12][144][8]
// rows 0..2 & 131..133 full; rows 3..130 cols {0..2, 131..143}
__global__ __launch_bounds__(256) void zero_feat2_halo(u16* __restrict__ f) {
    constexpr int FULLROWS = 6 * 12 * 144;      // 10368 slots
    constexpr int PER_B = FULLROWS + 128 * 12 * 16;  // 34944 slots
    int idx = blockIdx.x * 256 + threadIdx.x;
    if (idx >= 16 * PER_B) return;
    int b = idx / PER_B;
    int r = idx - b * PER_B;
    int row, cg, x;
    if (r < FULLROWS) {
        x = r % 144; int t = r / 144;
        cg = t % 12; int k = t / 12;            // 0..5
        row = k < 3 ? k : 128 + k;              // 0,1,2,131,132,133
    } else {
        int rr = r - FULLROWS;
        int c0 = rr & 15; int t = rr >> 4;
        cg = t % 12; row = 3 + t / 12;          // 3..130
        x = c0 < 3 ? c0 : c0 + 128;             // 0..2, 131..143
    }
    *(short8*)(f + ((((size_t)(b * 134) + row) * 12 + cg) * 144 + x) * 8) =
        (short8){0, 0, 0, 0, 0, 0, 0, 0};
}

// ---------------- upflow: transposed conv, lhs_dilation=2, pad=2, k=4, groups=2
__global__ __launch_bounds__(256) void upflow_kernel(const float* __restrict__ tflow, const float* __restrict__ wu,
                                                     float* __restrict__ flow) {
    int gid = blockIdx.x * 256 + threadIdx.x;   // 524288 exact
    int x = gid & 127;
    int y = (gid >> 7) & 127;
    int c = (gid >> 14) & 1;
    int b = gid >> 15;
    float acc = 0.f;
#pragma unroll
    for (int ky = 0; ky < 4; ++ky) {
        int u = y + ky - 2;
        if ((u & 1) || u < 0 || u > 126) continue;
        int iy = u >> 1;
#pragma unroll
        for (int kx = 0; kx < 4; ++kx) {
            int v = x + kx - 2;
            if ((v & 1) || v < 0 || v > 126) continue;
            int ix = v >> 1;
            acc += tflow[((b * 2 + c) * 64 + iy) * 64 + ix] *
                   wu[c * 16 + (3 - ky) * 4 + (3 - kx)];
        }
    }
    flow[gid] = acc;
}

// ---------------- backward warp -> fragment-native bf16 feat2 [b][row 134][cg 12][x 144][8]
__global__ __launch_bounds__(256) void warp_kernel(const float* __restrict__ second, const float* __restrict__ flow,
                                                   u16* __restrict__ feat2) {
    int tid = threadIdx.x;
    int x = tid & 127;
    int half = tid >> 7;            // 0..1
    int blk = blockIdx.x;           // (b*128 + y)*6 + cgp
    int cgp = blk % 6;
    int t = blk / 6;
    int y = t & 127;
    int b = t >> 7;
    int cg = cgp * 2 + half;        // 0..11

    float fx = (float)x + 2.5f * flow[((b * 2 + 0) * HW + y) * HW + x];
    float fy = (float)y + 2.5f * flow[((b * 2 + 1) * HW + y) * HW + x];
    float x0f = floorf(fx), y0f = floorf(fy);
    int x0 = (int)x0f, y0 = (int)y0f;
    int x1 = x0 + 1, y1 = y0 + 1;
    float wx1 = fx - x0f, wx0 = (x0f + 1.f) - fx;
    float wy1 = fy - y0f, wy0 = (y0f + 1.f) - fy;
    float wA = wx0 * wy0, wB = wx1 * wy0, wC = wx0 * wy1, wD = wx1 * wy1;
    float vA = (x0 >= 0 && x0 <= 127 && y0 >= 0 && y0 <= 127) ? 1.f : 0.f;
    float vB = (x1 >= 0 && x1 <= 127 && y0 >= 0 && y0 <= 127) ? 1.f : 0.f;
    float vC = (x0 >= 0 && x0 <= 127 && y1 >= 0 && y1 <= 127) ? 1.f : 0.f;
    float vD = (x1 >= 0 && x1 <= 127 && y1 >= 0 && y1 <= 127) ? 1.f : 0.f;
    wA *= vA; wB *= vB; wC *= vC; wD *= vD;
    float ones = wA + wB + wC + wD;
    float maskf = (ones > 0.999f) ? 1.f : 0.f;
    wA *= maskf; wB *= maskf; wC *= maskf; wD *= maskf;
    int xc0 = min(max(x0, 0), 127), xc1 = min(max(x1, 0), 127);
    int yc0 = min(max(y0, 0), 127), yc1 = min(max(y1, 0), 127);
    int i00 = yc0 * HW + xc0, i01 = yc0 * HW + xc1;
    int i10 = yc1 * HW + xc0, i11 = yc1 * HW + xc1;

    const float* base = second + (size_t)b * 96 * HW * HW + (size_t)(cg * 8) * (HW * HW);
    short8 o;
#pragma unroll
    for (int j = 0; j < 8; ++j) {
        const float* pp = base + (size_t)j * (HW * HW);
        float v = wA * pp[i00] + wB * pp[i01] + wC * pp[i10] + wD * pp[i11];
        o[j] = (short)f2bf(v);
    }
    *(short8*)(feat2 + ((((size_t)(b * 134) + y + 3) * 12 + cg) * 144 + (x + 3)) * 8) = o;
}

// ---------------- correlation as banded MFMA GEMM -> NHWC (16,130,130,64) bf16 corr, + /96 + lrelu
// XCD-swizzled grid: each XCD owns 2 batches (512 contiguous logical blocks) -> feat2 dy-window
// stays in that XCD's L2. A-tile (first, fp32) staged via LDS: coalesced dwordx4 loads,
// fragment build from LDS (row stride 70 words -> 2-way bank alias = free).
__global__ __launch_bounds__(256) void corr_mfma(const float* __restrict__ first, const u16* __restrict__ feat2,
                                                 u16* __restrict__ corrp) {
    __shared__ float ldsF[96 * 70];      // 26880 B
    int tid = threadIdx.x;
    int wave = tid >> 6, lane = tid & 63;
    int quad = lane >> 4, l16 = lane & 15;
    // bijective XCD swizzle: 4096 blocks -> 8 chunks of 512
    int swz = (blockIdx.x & 7) * 512 + (blockIdx.x >> 3);
    int half = swz & 1;
    int y = (swz >> 1) & 127;
    int b = swz >> 8;
    int x0 = (half * 4 + wave) * 16;

    // stage first[b, 0..95, y, half*64 .. half*64+63] -> ldsF[ch][px]
    {
        const float* fb = first + ((size_t)(b * 96) * HW + y) * HW + half * 64;
#pragma unroll
        for (int i = 0; i < 6; ++i) {
            int id = i * 256 + tid;          // 0..1535
            int ch = id >> 4;                // 0..95
            int pq = (id & 15) * 4;          // px 0..60
            f32x4 v = *(const f32x4*)(fb + (size_t)ch * (HW * HW) + pq);
            ldsF[ch * 70 + pq + 0] = v[0];
            ldsF[ch * 70 + pq + 1] = v[1];
            ldsF[ch * 70 + pq + 2] = v[2];
            ldsF[ch * 70 + pq + 3] = v[3];
        }
    }
    __syncthreads();

    short8 afr[3];
    int col = wave * 16 + l16;               // px within the 64-px half
#pragma unroll
    for (int ch = 0; ch < 3; ++ch) {
        short8 a;
#pragma unroll
        for (int j = 0; j < 8; ++j)
            a[j] = (short)f2bf(ldsF[(ch * 32 + quad * 8 + j) * 70 + col]);
        afr[ch] = a;
    }

    f32x4 acc[7][2];
#pragma unroll
    for (int dy = 0; dy < 7; ++dy) {
        acc[dy][0] = (f32x4){0.f, 0.f, 0.f, 0.f};
        acc[dy][1] = (f32x4){0.f, 0.f, 0.f, 0.f};
    }

#pragma unroll
    for (int dy = 0; dy < 7; ++dy) {
#pragma unroll
        for (int ch = 0; ch < 3; ++ch) {
            const u16* rp = feat2 + ((((size_t)(b * 134) + y + dy) * 12 + ch * 4 + quad) * 144 + x0 + l16) * 8;
            short8 b0 = *(const short8*)(rp);
            short8 b1 = *(const short8*)(rp + 16 * 8);
            acc[dy][0] = __builtin_amdgcn_mfma_f32_16x16x32_bf16(afr[ch], b0, acc[dy][0], 0, 0, 0);
            acc[dy][1] = __builtin_amdgcn_mfma_f32_16x16x32_bf16(afr[ch], b1, acc[dy][1], 0, 0, 0);
        }
    }

    u16* op = corrp + ((size_t)(b * 130) + y + 1) * (130 * 64);
#pragma unroll
    for (int dy = 0; dy < 7; ++dy)
#pragma unroll
        for (int nt = 0; nt < 2; ++nt)
#pragma unroll
            for (int r = 0; r < 4; ++r) {
                int m = quad * 4 + r;
                int dx = nt * 16 + l16 - m;
                if (dx >= 0 && dx < 7) {
                    float v = lrelu_f(acc[dy][nt][r] * (1.f / 96.f));
                    op[(size_t)(x0 + m + 1) * 64 + dy * 7 + dx] = f2bf(v);
                }
            }

    // pad channels 49..63 must be zero (weights for ic>=49 are zero, but memory may be NaN)
    if (l16 < 15) {
#pragma unroll
        for (int r = 0; r < 4; ++r) {
            int m = quad * 4 + r;
            op[(size_t)(x0 + m + 1) * 64 + 49 + l16] = 0;
        }
    }
}

// ---------------- MFMA conv 3x3: stage-once-per-ch-group + 2-phase double-buffered LDS.
// Block: 2 output rows x 128 px x OCB oc, 4 waves. K-loop over NCH ch-groups;
// all 9 taps read the staged LDS tile (4 rows x 144 px-slots x 32 ch, 36.9KB/buf).
// Per step: ISSUE async stage of step s+1 into back buffer FIRST, then compute step s
// from front buffer, then one __syncthreads() (drains vmcnt+lgkm) -> T3-minimum overlap.
// Granule swizzle: within each 64B px-slot, ch-quad q lives at granule (q ^ (px>>1))&3
// (bank-conflict-free ds_read_b128). Staging stays linear global_load_lds with the
// permutation folded into the per-lane SOURCE address.
template<int ICP, int OC, int OCB, int PADOUT>
__global__ __launch_bounds__(256, 2) void conv_mfma(const u16* __restrict__ in, const u16* __restrict__ wp,
                                                    const float* __restrict__ bias, u16* __restrict__ out) {
    constexpr int NCH = ICP / 32;
    constexpr int NOCT = OCB / 16;
    constexpr int OCG = OC / OCB;
    constexpr int Wi = 130;
    constexpr int Wo = 128 + 2 * PADOUT;

    __shared__ __align__(16) u16 ldsA[2][4 * 144 * 32];   // double-buffered, granule-permuted

    int tid = threadIdx.x;
    int wave = tid >> 6, lane = tid & 63;
    int quad = lane >> 4, l16 = lane & 15;

    // bijective chunked XCD swizzle (gridDim % 8 == 0)
    int cpx = gridDim.x >> 3;
    int bid = blockIdx.x;
    int swz = (bid & 7) * cpx + (bid >> 3);
    int rowpair = swz & 63;
    int t = swz >> 6;
    int ocg = t % OCG;
    int b = t / OCG;
    int row_blk = rowpair * 2;
    int row_h = wave >> 1;          // wave's output row within the pair
    int px0 = (wave & 1) * 64;      // wave's 64-px half

    int pxl = lane >> 2;            // staging: lane -> px within 16-px chunk
    int g   = lane & 3;             // staging: lane -> granule within 64B slot

    auto stageA = [&](int s) {
        const u16* rbase = in + ((size_t)(b * Wi + row_blk + wave) * Wi) * ICP + s * 32;
        u16* lbase = &ldsA[s & 1][wave * (144 * 32)];
#pragma unroll
        for (int c = 0; c < 9; ++c) {
            int px = c * 16 + pxl;
            int q = (g ^ (px >> 1)) & 3;       // which ch-quad this granule holds
            int pxg = px > 129 ? 129 : px;     // clamp pad slots to valid memory
            gload_lds16(rbase + (size_t)pxg * ICP + q * 8, lbase + c * 16 * 32);
        }
    };

    f32x4 acc[4][NOCT];
#pragma unroll
    for (int mt = 0; mt < 4; ++mt)
#pragma unroll
        for (int ot = 0; ot < NOCT; ++ot)
            acc[mt][ot] = (f32x4){0.f, 0.f, 0.f, 0.f};

    stageA(0);
    __syncthreads();

    for (int s = 0; s < NCH; ++s) {
        if (s + 1 < NCH) stageA(s + 1);        // async prefetch FIRST, hides under MFMAs
        const u16* lA = &ldsA[s & 1][0];
#pragma unroll
        for (int ky = 0; ky < 3; ++ky) {
#pragma unroll
            for (int kx = 0; kx < 3; ++kx) {
                const u16* bptr = wp + ((((size_t)(ky * 3 + kx) * NCH + s) * 4 + quad) * OC + ocg * OCB + l16) * 8;
                short8 bfr[NOCT];
#pragma unroll
                for (int ot = 0; ot < NOCT; ++ot)
                    bfr[ot] = *(const short8*)(bptr + ot * 16 * 8);
                short8 afr[4];
#pragma unroll
                for (int mt = 0; mt < 4; ++mt) {
                    int rpx = px0 + kx + mt * 16 + l16;
                    int gg = (quad ^ (rpx >> 1)) & 3;
                    afr[mt] = *(const short8*)&lA[((row_h + ky) * 144 + rpx) * 32 + gg * 8];
                }
#pragma unroll
                for (int mt = 0; mt < 4; ++mt)
#pragma unroll
                    for (int ot = 0; ot < NOCT; ++ot)
                        acc[mt][ot] = __builtin_amdgcn_mfma_f32_16x16x32_bf16(afr[mt], bfr[ot], acc[mt][ot], 0, 0, 0);
            }
        }
        __syncthreads();   // front buffer fully read; prefetch (vmcnt) drained
    }

    float bv[NOCT];
#pragma unroll
    for (int ot = 0; ot < NOCT; ++ot) bv[ot] = bias[ocg * OCB + ot * 16 + l16];

#pragma unroll
    for (int mt = 0; mt < 4; ++mt) {
#pragma unroll
        for (int ot = 0; ot < NOCT; ++ot) {
#pragma unroll
            for (int r = 0; r < 4; ++r) {
                int px = px0 + mt * 16 + quad * 4 + r;
                float v = lrelu_f(acc[mt][ot][r] + bv[ot]);
                out[((size_t)(b * Wo + row_blk + row_h + PADOUT) * Wo + px + PADOUT) * OC + ocg * OCB + ot * 16 + l16] = f2bf(v);
            }
        }
    }
}

// ---------------- conv4: 5x5, 32->2, NHWC pad-2 in (132x132x32), + flow add -> NCHW f32 out
__global__ __launch_bounds__(256) void conv4_kernel(const u16* __restrict__ in, const float* __restrict__ w4p,
                                                    const float* __restrict__ b4, const float* __restrict__ flow,
                                                    float* __restrict__ out) {
    int gid = blockIdx.x * 256 + threadIdx.x;   // 16*128*128
    int x = gid & 127;
    int y = (gid >> 7) & 127;
    int b = gid >> 14;
    float acc0 = b4[0], acc1 = b4[1];
#pragma unroll
    for (int ky = 0; ky < 5; ++ky) {
#pragma unroll
        for (int kx = 0; kx < 5; ++kx) {
            const u16* p = in + ((size_t)(b * 132 + y + ky) * 132 + x + kx) * 32;
            const float* wb = w4p + (ky * 5 + kx) * 64;
#pragma unroll
            for (int g = 0; g < 4; ++g) {
                short8 vv = *(const short8*)(p + g * 8);
#pragma unroll
                for (int j = 0; j < 8; ++j) {
                    float v = bf2f((u16)vv[j]);
                    acc0 += v * wb[g * 8 + j];
                    acc1 += v * wb[32 + g * 8 + j];
                }
            }
        }
    }
    int o0 = ((b * 2 + 0) * HW + y) * HW + x;
    int o1 = o0 + HW * HW;
    out[o0] = acc0 + flow[o0];
    out[o1] = acc1 + flow[o1];
}

// ---------------- launch
extern "C" void kernel_launch(void* const* d_in, const int* in_sizes, int n_in,
                              void* d_out, int out_size, void* d_ws, size_t ws_size,
                              hipStream_t stream) {
    const float* ffirst  = (const float*)d_in[2];
    const float* fsecond = (const float*)d_in[3];
    const float* tflow   = (const float*)d_in[4];
    const float* wu      = (const float*)d_in[5];
    const float* w1 = (const float*)d_in[6];
    const float* b1 = (const float*)d_in[7];
    const float* w2 = (const float*)d_in[8];
    const float* b2 = (const float*)d_in[9];
    const float* w3 = (const float*)d_in[10];
    const float* b3 = (const float*)d_in[11];
    const float* w4 = (const float*)d_in[12];
    const float* b4 = (const float*)d_in[13];
    float* out = (float*)d_out;
    char* ws = (char*)d_ws;

    // packed weights
    u16* w1p = (u16*)(ws + 0);         // 147456 B
    u16* w2p = (u16*)(ws + 147456);    // 147456 B
    u16* w3p = (u16*)(ws + 294912);    // 36864 B
    float* w4p = (float*)(ws + 331776);// 6400 B

    float* flow = (float*)(ws + 602112);   // 2097152 B, ends 2699264
    u16* regA = (u16*)(ws + 2699264);      // feat2 59.3MB -> x1p 69.2MB -> x3p 17.8MB
    u16* regB = (u16*)(ws + 71921664);     // corr 34.6MB -> x2p 34.6MB; end 106532864

    // 1) weight packing
    pack_w<49, 64, 128><<<288, 256, 0, stream>>>(w1, w1p);
    pack_w<128, 128, 64><<<288, 256, 0, stream>>>(w2, w2p);
    pack_w<64, 64, 32><<<72, 256, 0, stream>>>(w3, w3p);
    pack_w4<<<7, 256, 0, stream>>>(w4, w4p);

    // 2) upflow -> flow (f32 NCHW)
    upflow_kernel<<<2048, 256, 0, stream>>>(tflow, wu, flow);

    // 3) warp -> feat2 fragment-native [16][134][12][144][8] bf16 (halo zeroed, no full memset)
    zero_feat2_halo<<<2184, 256, 0, stream>>>(regA);
    warp_kernel<<<12288, 256, 0, stream>>>(fsecond, flow, regA);

    // 4) correlation (banded MFMA) + lrelu -> corr NHWC (130,130,64) bf16
    zero_border<130, 1, 128, 64><<<33, 256, 0, stream>>>(regB);
    corr_mfma<<<4096, 256, 0, stream>>>(ffirst, regA, regB);

    // 5) conv1 64->128 MFMA -> x1p NHWC pad1 (feat2 dead after corr; zero x1p border only)
    zero_border<130, 1, 128, 128><<<33, 256, 0, stream>>>(regA);
    conv_mfma<64, 128, 64, 1><<<2048, 256, 0, stream>>>(regB, w1p, b1, regA);

    // 6) conv2 128->64 MFMA -> x2p NHWC pad1 (corr dead after conv1)
    zero_border<130, 1, 128, 64><<<33, 256, 0, stream>>>(regB);
    conv_mfma<128, 64, 64, 1><<<1024, 256, 0, stream>>>(regA, w2p, b2, regB);

    // 7) conv3 64->32 MFMA -> x3p NHWC pad2 (x1 dead after conv2)
    zero_border<132, 2, 128, 32><<<65, 256, 0, stream>>>(regA);
    conv_mfma<64, 32, 32, 2><<<1024, 256, 0, stream>>>(regB, w3p, b3, regA);

    // 8) conv4 5x5 32->2 + flow add -> d_out (f32 NCHW)
    conv4_kernel<<<1024, 256, 0, stream>>>(regA, w4p, b4, flow, out);
}